// Round 1
// 10389.476 us; speedup vs baseline: 1.9505x; 1.9505x over previous
//
#include <hip/hip_runtime.h>
#include <hip/hip_bf16.h>
#include <math.h>

// Problem constants
#define T_STEPS 256
#define BATCH   8
#define HID     1024
#define NROWS   2048            // T*B
#define GATE6   6144            // 4H (i,f,g,o) + H (gc) + H (go)
#define VOCAB   50257
#define NBLK    256             // persistent-kernel workgroups (1 per CU)

// -------------------------------------------------------------------------
// Embedding gather: e[row,:] = emb[x[row],:]   row = t*B+b
// -------------------------------------------------------------------------
__global__ void embed_kernel(const int* __restrict__ x,
                             const float* __restrict__ emb,
                             float* __restrict__ e) {
    int row = blockIdx.x;
    int v = x[row];
    const float4* src = (const float4*)(emb + (size_t)v * HID);
    float4* dst = (float4*)(e + (size_t)row * HID);
    dst[threadIdx.x] = src[threadIdx.x];    // 256 threads * float4 = 1024
}

// -------------------------------------------------------------------------
// SGEMM  C[m,n] = sum_k A[m,k]*B[n,k] + bias1[n] + bias2[n]
// A row-major [M x K] (lda), B row-major [N x K] (ldb), C (ldc).
// Tiles: BM=128, BN=64, BK=16; 256 threads; thread tile 8x4.
// -------------------------------------------------------------------------
__global__ __launch_bounds__(256) void sgemm_tn(
    const float* __restrict__ A, int lda,
    const float* __restrict__ Bm, int ldb,
    float* __restrict__ C, int ldc,
    const float* __restrict__ bias1,
    const float* __restrict__ bias2,
    int N, int K)
{
    __shared__ float As[128][20];   // stride 20: float4-aligned, bank-friendly
    __shared__ float Bs[16][68];    // stride 68: float4-aligned, bank-friendly

    const int tid = threadIdx.x;
    const int m0 = blockIdx.y * 128;
    const int n0 = blockIdx.x * 64;
    const int ty = tid >> 4;        // 0..15 : rows ty*8..ty*8+7
    const int tx = tid & 15;        // 0..15 : cols tx*4..tx*4+3

    float acc[8][4];
#pragma unroll
    for (int i = 0; i < 8; ++i)
#pragma unroll
        for (int j = 0; j < 4; ++j) acc[i][j] = 0.0f;

    for (int k0 = 0; k0 < K; k0 += 16) {
        __syncthreads();
        // Stage A: 128x16 floats, 2 float4 per thread
#pragma unroll
        for (int i = 0; i < 2; ++i) {
            int f4 = tid + (i << 8);
            int row = f4 >> 2;
            int kc = (f4 & 3) << 2;
            float4 v = *(const float4*)(A + (size_t)(m0 + row) * lda + k0 + kc);
            *(float4*)(&As[row][kc]) = v;
        }
        // Stage B (transposed): 64x16 floats, 1 float4 per thread
        {
            int n = tid >> 2;
            int kc = (tid & 3) << 2;
            float4 v = make_float4(0.f, 0.f, 0.f, 0.f);
            if (n0 + n < N)
                v = *(const float4*)(Bm + (size_t)(n0 + n) * ldb + k0 + kc);
            Bs[kc + 0][n] = v.x; Bs[kc + 1][n] = v.y;
            Bs[kc + 2][n] = v.z; Bs[kc + 3][n] = v.w;
        }
        __syncthreads();
#pragma unroll
        for (int kk = 0; kk < 16; ++kk) {
            float a[8];
#pragma unroll
            for (int i = 0; i < 8; ++i) a[i] = As[ty * 8 + i][kk];
            float4 b4 = *(const float4*)(&Bs[kk][tx << 2]);
#pragma unroll
            for (int i = 0; i < 8; ++i) {
                acc[i][0] += a[i] * b4.x;
                acc[i][1] += a[i] * b4.y;
                acc[i][2] += a[i] * b4.z;
                acc[i][3] += a[i] * b4.w;
            }
        }
    }

    int col = n0 + (tx << 2);
    float bsum[4];
#pragma unroll
    for (int j = 0; j < 4; ++j) {
        float bs = 0.f;
        int c_ = col + j;
        if (c_ < N) {
            if (bias1) bs += bias1[c_];
            if (bias2) bs += bias2[c_];
        }
        bsum[j] = bs;
    }
#pragma unroll
    for (int i = 0; i < 8; ++i) {
        size_t off = (size_t)(m0 + ty * 8 + i) * ldc + col;
        if ((col + 3 < N) && ((off & 3) == 0)) {
            float4 v = make_float4(acc[i][0] + bsum[0], acc[i][1] + bsum[1],
                                   acc[i][2] + bsum[2], acc[i][3] + bsum[3]);
            *(float4*)(C + off) = v;
        } else {
#pragma unroll
            for (int j = 0; j < 4; ++j)
                if (col + j < N) C[off + j] = acc[i][j] + bsum[j];
        }
    }
}

// -------------------------------------------------------------------------
// Persistent recurrent kernel: 256 WGs x 256 threads, loops t = 0..255.
// WG j owns h-dims d in [4j, 4j+4) -> 24 weight rows (6 gates x 4 dims).
// Thread (r = tid/8 in [0,24), ks = tid%8) computes a 128-long K-chunk of
// row r's dot with h for all 8 batches; shuffle-reduce over ks.
//
// COHERENCE DESIGN (this revision): all cross-WG communication (h exchange
// + barrier) uses RELAXED agent-scope atomics. Relaxed scoped accesses set
// the per-instruction sc bits (write-through / L2-bypass to the LLC) but
// emit NO buffer_wbl2 / buffer_inv cache maintenance. The previous
// acquire/release version invalidated the whole XCD L2 on every barrier
// poll, evicting the (otherwise L2-resident) 96 KB/CU of recurrent weights
// every step. Ordering is enforced manually:
//   h stores (sc1) -> s_waitcnt vmcnt(0) -> grp add -> central add -> flag.
// Barrier counters are MONOTONIC (no resets), so there is no
// reset-vs-increment store-ordering hazard between different addresses.
// -------------------------------------------------------------------------
__device__ inline float sigm(float x) { return 1.0f / (1.0f + expf(-x)); }

__global__ __launch_bounds__(256) void recurrent_kernel(
    const float* __restrict__ Xp,    // [2048][6144] x-projections (+ biases)
    const float* __restrict__ whh,   // [4096][1024]
    const float* __restrict__ wgc,   // [1024][2048] (h-part at col offset 1024)
    const float* __restrict__ wgo,   // [1024][2048]
    const float* __restrict__ blend, // [4]
    const float* __restrict__ c0,    // [8][1024] layer slice
    float* __restrict__ y,           // [2048][1024] layer output
    float* __restrict__ hT,          // [8][1024] in d_out
    float* __restrict__ cT,          // [8][1024] in d_out
    float* __restrict__ hbuf,        // [2][8][1024] double buffer
    unsigned int* __restrict__ bar,  // barrier region (zeroed once per launch seq)
    unsigned int phase0)
{
    // LDS: h staged with per-chunk skew of 4 floats (stride 132 per 128-chunk)
    // so 8 distinct ks-addresses hit banks {0,4,...,28}: conflict-free b128.
    __shared__ float hs[8 * 1056];
    __shared__ float recbuf[192];    // [24 rows][8 batch]

    const int tid = threadIdx.x;
    const int j = blockIdx.x;

    // softmax blend probs (tiny, computed by every thread)
    float e0 = expf(blend[0]), e1 = expf(blend[1]);
    float e2 = expf(blend[2]), e3 = expf(blend[3]);
    float p00 = e0 / (e0 + e1), p01 = e1 / (e0 + e1);
    float p10 = e2 / (e2 + e3), p11 = e3 / (e2 + e3);

    const int r = tid >> 3;          // 0..23 (active when tid<192)
    const int ks = tid & 7;          // K-chunk 0..7
    const float* wrow = whh;         // fixed per thread across all steps
    if (tid < 192) {
        int dloc = r / 6, g = r % 6;
        int d = j * 4 + dloc;
        if (g < 4)       wrow = whh + ((size_t)(g * HID + d)) * HID + ks * 128;
        else if (g == 4) wrow = wgc + (size_t)d * 2048 + HID + ks * 128;
        else             wrow = wgo + (size_t)d * 2048 + HID + ks * 128;
    }

    // update-phase lane state (tid < 32): b = tid&7, dloc = tid>>3
    const int ub = tid & 7, udl = tid >> 3;
    const int ud = j * 4 + udl;
    float c_prev = (tid < 32) ? c0[ub * HID + ud] : 0.0f;

    for (int t = 0; t < T_STEPS; ++t) {
        const float* cur = hbuf + (t & 1) * 8192;
        float* nxt = hbuf + ((t + 1) & 1) * 8192;

        // Prefetch this step's x-projections early (independent of h)
        float xv[6];
        if (tid < 32) {
            const float* xr = Xp + (size_t)(t * 8 + ub) * GATE6 + ud;
#pragma unroll
            for (int q = 0; q < 6; ++q) xv[q] = xr[q * 1024];
        }

        // Stage h -> LDS (swizzled): idx = b*1056 + k + (k>>7)*4
        // Relaxed agent-scope scalar loads: bypass (possibly stale) L1/L2,
        // read the LLC where producers' write-through stores landed.
        // No cache-maintenance ops emitted.
#pragma unroll
        for (int it = 0; it < 8; ++it) {
            int k = tid * 4;
            const float* src = cur + it * 1024 + k;
            float4 v;
            v.x = __hip_atomic_load(src + 0, __ATOMIC_RELAXED, __HIP_MEMORY_SCOPE_AGENT);
            v.y = __hip_atomic_load(src + 1, __ATOMIC_RELAXED, __HIP_MEMORY_SCOPE_AGENT);
            v.z = __hip_atomic_load(src + 2, __ATOMIC_RELAXED, __HIP_MEMORY_SCOPE_AGENT);
            v.w = __hip_atomic_load(src + 3, __ATOMIC_RELAXED, __HIP_MEMORY_SCOPE_AGENT);
            int idx = it * 1056 + k + ((k >> 7) << 2);
            *(float4*)(&hs[idx]) = v;
        }
        __syncthreads();

        float acc[8];
#pragma unroll
        for (int b = 0; b < 8; ++b) acc[b] = 0.0f;
        if (tid < 192) {
            const int hbase = ks * 132;
#pragma unroll 4
            for (int kk = 0; kk < 128; kk += 4) {
                float4 wv = *(const float4*)(wrow + kk);
#pragma unroll
                for (int b = 0; b < 8; ++b) {
                    float4 hv = *(const float4*)(&hs[b * 1056 + hbase + kk]);
                    acc[b] += wv.x * hv.x + wv.y * hv.y + wv.z * hv.z + wv.w * hv.w;
                }
            }
        }
        // reduce over ks (lanes differing in low 3 bits, same wave)
#pragma unroll
        for (int off = 1; off < 8; off <<= 1) {
#pragma unroll
            for (int b = 0; b < 8; ++b) acc[b] += __shfl_xor(acc[b], off, 64);
        }
        if (tid < 192 && ks == 0) {
#pragma unroll
            for (int b = 0; b < 8; ++b) recbuf[r * 8 + b] = acc[b];
        }
        __syncthreads();

        // Gate assembly + state update (wave 0, lanes 0..31)
        if (tid < 32) {
            float pi  = xv[0] + recbuf[(udl * 6 + 0) * 8 + ub];
            float pf  = xv[1] + recbuf[(udl * 6 + 1) * 8 + ub];
            float pg  = xv[2] + recbuf[(udl * 6 + 2) * 8 + ub];
            float po  = xv[3] + recbuf[(udl * 6 + 3) * 8 + ub];
            float pgc = xv[4] + recbuf[(udl * 6 + 4) * 8 + ub];
            float pgo = xv[5] + recbuf[(udl * 6 + 5) * 8 + ub];
            float gg = tanhf(pg) * p00 + tanhf(pgc) * p01;
            float go = sigm(po) * p10 + sigm(pgo) * p11;
            float c  = sigm(pf) * c_prev + sigm(pi) * gg;
            c_prev = c;
            float h = go * tanhf(c);
            y[(size_t)(t * 8 + ub) * HID + ud] = h;
            // write-through (sc1) store: visible at LLC once vmcnt retires
            __hip_atomic_store(&nxt[ub * HID + ud], h,
                               __ATOMIC_RELAXED, __HIP_MEMORY_SCOPE_AGENT);
            if (t == T_STEPS - 1) {
                hT[ub * HID + ud] = h;
                cT[ub * HID + ud] = c;
            }
        }

        // ---- grid barrier: monotonic two-level, ALL RELAXED atomics ----
        __syncthreads();
        if (tid == 0) {
            // drain wave 0's h stores to the coherence point before arrival
            asm volatile("s_waitcnt vmcnt(0)" ::: "memory");
            unsigned gs = phase0 + (unsigned)t + 1u;   // global step number
            unsigned* central = bar;
            unsigned* flag = bar + 32;
            unsigned* grp = bar + 64 + (j >> 4) * 32;
            unsigned gprev = __hip_atomic_fetch_add(grp, 1u, __ATOMIC_RELAXED,
                                                    __HIP_MEMORY_SCOPE_AGENT);
            bool done = false;
            if (gprev == 16u * gs - 1u) {          // last arriver of this group
                unsigned cprev = __hip_atomic_fetch_add(central, 1u,
                                __ATOMIC_RELAXED, __HIP_MEMORY_SCOPE_AGENT);
                if (cprev == 16u * gs - 1u) {      // last group overall
                    __hip_atomic_store(flag, gs, __ATOMIC_RELAXED,
                                       __HIP_MEMORY_SCOPE_AGENT);
                    done = true;
                }
            }
            if (!done) {
                while (__hip_atomic_load(flag, __ATOMIC_RELAXED,
                                         __HIP_MEMORY_SCOPE_AGENT) < gs)
                    __builtin_amdgcn_s_sleep(1);
            }
        }
        __syncthreads();
    }
}

// -------------------------------------------------------------------------
extern "C" void kernel_launch(void* const* d_in, const int* in_sizes, int n_in,
                              void* d_out, int out_size, void* d_ws, size_t ws_size,
                              hipStream_t stream) {
    const int*   x     = (const int*)d_in[0];
    const float* h0    = (const float*)d_in[1];
    const float* c0    = (const float*)d_in[2];
    const float* emb   = (const float*)d_in[3];
    const float* w_dec = (const float*)d_in[4];
    const float* b_dec = (const float*)d_in[5];
    const float* wih[2]   = {(const float*)d_in[6],  (const float*)d_in[15]};
    const float* bih[2]   = {(const float*)d_in[7],  (const float*)d_in[16]};
    const float* whh[2]   = {(const float*)d_in[8],  (const float*)d_in[17]};
    const float* bhh[2]   = {(const float*)d_in[9],  (const float*)d_in[18]};
    const float* blend[2] = {(const float*)d_in[10], (const float*)d_in[19]};
    const float* wgc[2]   = {(const float*)d_in[11], (const float*)d_in[20]};
    const float* bgc[2]   = {(const float*)d_in[12], (const float*)d_in[21]};
    const float* wgo[2]   = {(const float*)d_in[13], (const float*)d_in[22]};
    const float* bgo[2]   = {(const float*)d_in[14], (const float*)d_in[23]};

    float* out = (float*)d_out;
    char* ws = (char*)d_ws;
    size_t off = 0;
    auto alloc = [&](size_t bytes) -> char* {
        char* p = ws + off;
        off += (bytes + 255) & ~(size_t)255;
        return p;
    };
    float* e    = (float*)alloc(sizeof(float) * (size_t)NROWS * HID);    // 8 MB
    float* Xp   = (float*)alloc(sizeof(float) * (size_t)NROWS * GATE6);  // 50 MB
    float* y0   = (float*)alloc(sizeof(float) * (size_t)NROWS * HID);    // 8 MB
    float* hbuf = (float*)alloc(sizeof(float) * 2 * BATCH * HID);
    unsigned* bar = (unsigned*)alloc(4096);
    float* y1 = e;  // e is dead after layer-0 projections; reuse for y1

    hipMemsetAsync(bar, 0, 4096, stream);
    embed_kernel<<<NROWS, 256, 0, stream>>>(x, emb, e);

    float* outH = out + (size_t)NROWS * VOCAB;      // hids at 102,926,336
    float* outC = outH + 2 * BATCH * HID;           // cells

    const float* Ain = e;
    float* yl[2] = {y0, y1};
    for (int l = 0; l < 2; ++l) {
        // x-projections (biases folded): cols [0,4096)=i,f,g,o ; [4096,5120)=gc ; [5120,6144)=go
        sgemm_tn<<<dim3(4096 / 64, NROWS / 128), 256, 0, stream>>>(
            Ain, HID, wih[l], HID, Xp, GATE6, bih[l], bhh[l], 4096, HID);
        sgemm_tn<<<dim3(1024 / 64, NROWS / 128), 256, 0, stream>>>(
            Ain, HID, wgc[l], 2048, Xp + 4096, GATE6, bgc[l], nullptr, 1024, HID);
        sgemm_tn<<<dim3(1024 / 64, NROWS / 128), 256, 0, stream>>>(
            Ain, HID, wgo[l], 2048, Xp + 5120, GATE6, bgo[l], nullptr, 1024, HID);
        hipMemcpyAsync(hbuf, h0 + (size_t)l * BATCH * HID,
                       sizeof(float) * BATCH * HID, hipMemcpyDeviceToDevice, stream);
        recurrent_kernel<<<NBLK, 256, 0, stream>>>(
            Xp, whh[l], wgc[l], wgo[l], blend[l], c0 + (size_t)l * BATCH * HID,
            yl[l], outH + (size_t)l * BATCH * HID, outC + (size_t)l * BATCH * HID,
            hbuf, bar, (unsigned)(l * T_STEPS));
        Ain = yl[l];
    }

    // Decoder: out[row, v] = y1[row,:] . w_dec[v,:] + b_dec[v]
    sgemm_tn<<<dim3((VOCAB + 63) / 64, NROWS / 128), 256, 0, stream>>>(
        y1, HID, w_dec, HID, out, VOCAB, b_dec, nullptr, VOCAB, HID);
}